// Round 1
// baseline (120.049 us; speedup 1.0000x reference)
//
#include <hip/hip_runtime.h>
#include <cstdint>
#include <cstddef>

typedef __bf16 bf16x8 __attribute__((ext_vector_type(8)));
typedef unsigned short u16x8 __attribute__((ext_vector_type(8)));
typedef float f32x4 __attribute__((ext_vector_type(4)));

#define MFMA(a, b, c) __builtin_amdgcn_mfma_f32_16x16x32_bf16(a, b, c, 0, 0, 0)

__device__ __forceinline__ unsigned short f2bfbits(float x) {
    unsigned u = __builtin_bit_cast(unsigned, x);
    u += 0x7FFFu + ((u >> 16) & 1u);           // round-to-nearest-even
    return (unsigned short)(u >> 16);
}

__device__ __forceinline__ bf16x8 pack8(f32x4 a, f32x4 b) {
    u16x8 t;
    t[0] = f2bfbits(a[0]); t[1] = f2bfbits(a[1]);
    t[2] = f2bfbits(a[2]); t[3] = f2bfbits(a[3]);
    t[4] = f2bfbits(b[0]); t[5] = f2bfbits(b[1]);
    t[6] = f2bfbits(b[2]); t[7] = f2bfbits(b[3]);
    return __builtin_bit_cast(bf16x8, t);
}

// ---------------------------------------------------------------------------
// Kernel 1: projections.  grid.x = 128 m-tiles * 4 matrices.
//   mat 0: Q = q_data@Wq  -> Qb   bf16 [B,H,2048,32]
//   mat 1: K = m_data@Wk  -> Kb   bf16 [B,H,2048,32]
//   mat 2: V = m_data@Wv  -> VT   bf16 [B,H,32,2048]  (transposed via LDS)
//   mat 3: gate = sigmoid(q_data@Wg + bg) -> f32 [B,N,128]
// Each WG: 4 waves, 64 rows; wave = 16 rows, full 128 cols via MFMA.
// ---------------------------------------------------------------------------
__global__ __launch_bounds__(256) void proj_kernel(
    const float* __restrict__ q_data, const float* __restrict__ m_data,
    const float* __restrict__ Wq, const float* __restrict__ Wk,
    const float* __restrict__ Wv, const float* __restrict__ Wg,
    const float* __restrict__ bg,
    unsigned short* __restrict__ Qb, unsigned short* __restrict__ Kb,
    unsigned short* __restrict__ VT, float* __restrict__ gate)
{
    __shared__ unsigned short vt_lds[128][80];   // pad 64->80 (16B-mult rows)
    const int mat   = blockIdx.x >> 7;
    const int mtile = blockIdx.x & 127;
    const int wave  = threadIdx.x >> 6;
    const int lane  = threadIdx.x & 63;
    const int r16 = lane & 15, g = lane >> 4;
    const int rowbase = mtile * 64 + wave * 16;

    const float* src = (mat == 1 || mat == 2) ? m_data : q_data;
    const float* W   = (mat == 0) ? Wq : (mat == 1) ? Wk : (mat == 2) ? Wv : Wg;

    // A fragments: 16 rows x 128 k (f32 -> bf16)
    bf16x8 afrag[4];
    {
        const float* arow = src + (size_t)(rowbase + r16) * 128;
        #pragma unroll
        for (int kk = 0; kk < 4; ++kk) {
            f32x4 lo = *(const f32x4*)(arow + kk * 32 + g * 8);
            f32x4 hi = *(const f32x4*)(arow + kk * 32 + g * 8 + 4);
            afrag[kk] = pack8(lo, hi);
        }
    }

    f32x4 acc[8];
    #pragma unroll
    for (int n0 = 0; n0 < 8; ++n0) {
        f32x4 a = {0.f, 0.f, 0.f, 0.f};
        #pragma unroll
        for (int kk = 0; kk < 4; ++kk) {
            f32x4 lo, hi;
            #pragma unroll
            for (int i = 0; i < 4; ++i) {
                lo[i] = W[(size_t)(kk * 32 + g * 8 + i) * 128 + n0 * 16 + r16];
                hi[i] = W[(size_t)(kk * 32 + g * 8 + 4 + i) * 128 + n0 * 16 + r16];
            }
            a = MFMA(afrag[kk], pack8(lo, hi), a);
        }
        acc[n0] = a;   // out[row=4g+i][col=n0*16+r16]
    }

    if (mat <= 1) {
        unsigned short* dst = (mat == 0) ? Qb : Kb;
        #pragma unroll
        for (int n0 = 0; n0 < 8; ++n0) {
            int n = n0 * 16 + r16, h = n >> 5, d = n & 31;
            #pragma unroll
            for (int i = 0; i < 4; ++i) {
                int grow = rowbase + 4 * g + i;
                int bb = grow >> 11, ns = grow & 2047;
                dst[(size_t)(bb * 4 + h) * 65536 + (size_t)ns * 32 + d] =
                    f2bfbits(acc[n0][i]);
            }
        }
    } else if (mat == 2) {
        #pragma unroll
        for (int n0 = 0; n0 < 8; ++n0) {
            int n = n0 * 16 + r16;
            #pragma unroll
            for (int i = 0; i < 4; ++i)
                vt_lds[n][wave * 16 + 4 * g + i] = f2bfbits(acc[n0][i]);
        }
        __syncthreads();
        int bb = rowbase >> 11;
        int nsbase = (mtile * 64) & 2047;
        #pragma unroll
        for (int it = 0; it < 4; ++it) {
            int idx = (threadIdx.x + it * 256) * 8;   // 128*64 elems
            int n = idx >> 6, mm = idx & 63;
            u16x8 v = *(const u16x8*)&vt_lds[n][mm];
            *(u16x8*)(VT + (size_t)(bb * 128 + n) * 2048 + nsbase + mm) = v;
        }
    } else {
        #pragma unroll
        for (int n0 = 0; n0 < 8; ++n0) {
            int n = n0 * 16 + r16;
            float bgv = bg[n];
            #pragma unroll
            for (int i = 0; i < 4; ++i) {
                int grow = rowbase + 4 * g + i;
                float x = acc[n0][i] + bgv;
                gate[(size_t)grow * 128 + n] = 1.0f / (1.0f + __expf(-x));
            }
        }
    }
}

// ---------------------------------------------------------------------------
// Kernel 2: flash attention + gate + output GEMM.
// grid.x = B * 128 q-tiles;  block = 256 (4 waves = 4 heads, same 16 q rows).
// Swapped QK^T: s = mfma(Kfrag, Qfrag) -> lane owns S[q=lane&15][k=4g+i].
// bias/nb adds are per-lane float4 loads (bias shared across the 4 waves ->
// L1 dedup).  P staged in per-wave XOR-swizzled LDS for the PV A-fragment;
// V read from VT (contiguous B-fragments).  Epilogue: gate, then @Wo + bo
// through LDS (wa never touches HBM).
// ---------------------------------------------------------------------------
__global__ __launch_bounds__(256) void attn_kernel(
    const unsigned short* __restrict__ Qb, const unsigned short* __restrict__ Kb,
    const unsigned short* __restrict__ VT, const float* __restrict__ gate,
    const float* __restrict__ bias, const float* __restrict__ nbias,
    const float* __restrict__ Wo, const float* __restrict__ bo,
    float* __restrict__ out)
{
    __shared__ char p_lds[4][2048];              // per-wave P tile 16x64 bf16
    __shared__ unsigned short wa_lds[16][136];   // gated wa, padded rows
    const int b  = blockIdx.x >> 7;
    const int qb = (blockIdx.x & 127) * 16;
    const int h    = threadIdx.x >> 6;
    const int lane = threadIdx.x & 63;
    const int q16 = lane & 15, g = lane >> 4;

    const size_t bh = (size_t)(b * 4 + h);
    const unsigned short* Qp = Qb + bh * 65536;
    const unsigned short* Kp = Kb + bh * 65536;
    const unsigned short* Vp = VT + bh * 65536;
    bf16x8 qfrag = *(const bf16x8*)(Qp + (size_t)(qb + q16) * 32 + g * 8);
    const float* brow = bias  + ((size_t)b * 2048 + qb + q16) * 2048;
    const float* nrow = nbias + ((size_t)h * 2048 + qb + q16) * 2048;
    char* pw = p_lds[h];
    const int swz = (q16 & 7) << 4;

    float m = -1e30f, ls = 0.f;
    f32x4 acc0 = {0, 0, 0, 0}, acc1 = {0, 0, 0, 0};

    for (int kb = 0; kb < 2048; kb += 64) {
        // ---- QK^T (swapped) ----
        f32x4 s[4];
        #pragma unroll
        for (int t = 0; t < 4; ++t) {
            bf16x8 kf = *(const bf16x8*)(Kp + (size_t)(kb + t * 16 + q16) * 32 + g * 8);
            f32x4 z = {0, 0, 0, 0};
            s[t] = MFMA(kf, qfrag, z);
        }
        // ---- biases ----
        #pragma unroll
        for (int t = 0; t < 4; ++t) {
            f32x4 bb = *(const f32x4*)(brow + kb + t * 16 + g * 4);
            f32x4 nn = *(const f32x4*)(nrow + kb + t * 16 + g * 4);
            s[t] += bb + nn;
        }
        // ---- online softmax ----
        float mx = -1e30f;
        #pragma unroll
        for (int t = 0; t < 4; ++t) {
            mx = fmaxf(mx, fmaxf(fmaxf(s[t][0], s[t][1]), fmaxf(s[t][2], s[t][3])));
        }
        mx = fmaxf(mx, __shfl_xor(mx, 16));
        mx = fmaxf(mx, __shfl_xor(mx, 32));
        float m_new = fmaxf(m, mx);
        float alpha = __expf(m - m_new);
        float psum = 0.f;
        #pragma unroll
        for (int t = 0; t < 4; ++t) {
            #pragma unroll
            for (int i = 0; i < 4; ++i) {
                float p = __expf(s[t][i] - m_new);
                s[t][i] = p;
                psum += p;
            }
        }
        psum += __shfl_xor(psum, 16);
        psum += __shfl_xor(psum, 32);
        ls = ls * alpha + psum;
        m = m_new;

        // ---- stage P (bf16) into swizzled per-wave LDS ----
        #pragma unroll
        for (int t = 0; t < 4; ++t) {
            uint2 pk;
            pk.x = (unsigned)f2bfbits(s[t][0]) | ((unsigned)f2bfbits(s[t][1]) << 16);
            pk.y = (unsigned)f2bfbits(s[t][2]) | ((unsigned)f2bfbits(s[t][3]) << 16);
            *(uint2*)(pw + ((q16 * 128 + t * 32 + g * 8) ^ swz)) = pk;
        }

        // ---- rescale accumulators (rows 4g+i) ----
        float al0 = __shfl(alpha, 4 * g + 0);
        float al1 = __shfl(alpha, 4 * g + 1);
        float al2 = __shfl(alpha, 4 * g + 2);
        float al3 = __shfl(alpha, 4 * g + 3);
        acc0[0] *= al0; acc0[1] *= al1; acc0[2] *= al2; acc0[3] *= al3;
        acc1[0] *= al0; acc1[1] *= al1; acc1[2] *= al2; acc1[3] *= al3;

        // ---- PV ----
        #pragma unroll
        for (int c = 0; c < 2; ++c) {
            bf16x8 pa = *(const bf16x8*)(pw + ((q16 * 128 + c * 64 + g * 16) ^ swz));
            bf16x8 v0 = *(const bf16x8*)(Vp + (size_t)q16 * 2048 + kb + c * 32 + g * 8);
            bf16x8 v1 = *(const bf16x8*)(Vp + (size_t)(16 + q16) * 2048 + kb + c * 32 + g * 8);
            acc0 = MFMA(pa, v0, acc0);
            acc1 = MFMA(pa, v1, acc1);
        }
    }

    // ---- epilogue: /l, gate, stage bf16 wa tile ----
    float ls0 = __shfl(ls, 4 * g + 0), ls1 = __shfl(ls, 4 * g + 1);
    float ls2 = __shfl(ls, 4 * g + 2), ls3 = __shfl(ls, 4 * g + 3);
    f32x4 inv = {1.f / ls0, 1.f / ls1, 1.f / ls2, 1.f / ls3};
    #pragma unroll
    for (int dt = 0; dt < 2; ++dt) {
        f32x4 a = dt ? acc1 : acc0;
        int col = h * 32 + dt * 16 + q16;
        #pragma unroll
        for (int i = 0; i < 4; ++i) {
            int row = 4 * g + i;
            float w = a[i] * inv[i];
            w *= gate[((size_t)b * 2048 + qb + row) * 128 + col];
            wa_lds[row][col] = f2bfbits(w);
        }
    }
    __syncthreads();

    // ---- out = wa @ Wo + bo; wave h computes cols [32h, 32h+32) ----
    f32x4 o0 = {0, 0, 0, 0}, o1 = {0, 0, 0, 0};
    #pragma unroll
    for (int kk = 0; kk < 4; ++kk) {
        bf16x8 a = *(const bf16x8*)&wa_lds[q16][kk * 32 + g * 8];
        f32x4 l0, h0, l1, h1;
        #pragma unroll
        for (int i = 0; i < 4; ++i) {
            int k0 = kk * 32 + g * 8 + i;
            int k1 = k0 + 4;
            l0[i] = Wo[(size_t)k0 * 128 + h * 32 + q16];
            h0[i] = Wo[(size_t)k1 * 128 + h * 32 + q16];
            l1[i] = Wo[(size_t)k0 * 128 + h * 32 + 16 + q16];
            h1[i] = Wo[(size_t)k1 * 128 + h * 32 + 16 + q16];
        }
        o0 = MFMA(a, pack8(l0, h0), o0);
        o1 = MFMA(a, pack8(l1, h1), o1);
    }
    float bo0 = bo[h * 32 + q16], bo1 = bo[h * 32 + 16 + q16];
    #pragma unroll
    for (int i = 0; i < 4; ++i) {
        int row = qb + 4 * g + i;
        out[((size_t)b * 2048 + row) * 128 + h * 32 + q16]      = o0[i] + bo0;
        out[((size_t)b * 2048 + row) * 128 + h * 32 + 16 + q16] = o1[i] + bo1;
    }
}

// ---------------------------------------------------------------------------
extern "C" void kernel_launch(void* const* d_in, const int* in_sizes, int n_in,
                              void* d_out, int out_size, void* d_ws, size_t ws_size,
                              hipStream_t stream)
{
    const float* q_data = (const float*)d_in[0];
    const float* m_data = (const float*)d_in[1];
    const float* bias   = (const float*)d_in[2];
    const float* nbias  = (const float*)d_in[3];
    const float* Wq     = (const float*)d_in[4];
    const float* Wk     = (const float*)d_in[5];
    const float* Wv     = (const float*)d_in[6];
    const float* Wg     = (const float*)d_in[7];
    const float* bg     = (const float*)d_in[8];
    const float* Wo     = (const float*)d_in[9];
    const float* bo     = (const float*)d_in[10];
    float* out = (float*)d_out;

    unsigned short* Qb = (unsigned short*)d_ws;          // 1M bf16 = 2MB
    unsigned short* Kb = Qb + (1 << 20);
    unsigned short* VT = Kb + (1 << 20);
    float* gate = (float*)(VT + (1 << 20));              // 4MB

    proj_kernel<<<dim3(512), dim3(256), 0, stream>>>(
        q_data, m_data, Wq, Wk, Wv, Wg, bg, Qb, Kb, VT, gate);
    attn_kernel<<<dim3(512), dim3(256), 0, stream>>>(
        Qb, Kb, VT, gate, bias, nbias, Wo, bo, out);
}